// Round 6
// baseline (366.087 us; speedup 1.0000x reference)
//
#include <hip/hip_runtime.h>

#define D 128

typedef unsigned int uint;
typedef unsigned short ushort;
typedef __attribute__((ext_vector_type(8))) short bf16x8_t;   // 8 bf16 = 4 VGPRs
typedef __attribute__((ext_vector_type(4))) float f32x4_t;    // MFMA accumulator

// ================= atomic-free CSR build: two-level bucket sort =================
// Level 1: partition edges by dst>>7 into nbuck buckets (782 for n=100000).
// Level 2: per-bucket (128 nodes, ~2K edges) LDS count/scan/rank -> CSR + dinv.
// All atomics are LDS-only; global writes are exact-offset scatters.
#define NB 256        // number of partition blocks (1 per CU -> full GPU)
#define BSH 7         // bucket shift: 128 nodes per bucket
#define BMASK 127
#define MAXBUCK 1024  // supports n <= 131072

__global__ __launch_bounds__(256) void kp_hist(const int* __restrict__ dst,
                                               int* __restrict__ table,
                                               int E, int nbuck, int chunk) {
    __shared__ int h[MAXBUCK];
    int t = threadIdx.x, b = blockIdx.x;
    for (int i = t; i < nbuck; i += 256) h[i] = 0;
    __syncthreads();
    int s = b * chunk, e = min(E, s + chunk);
    for (int i = s + t; i < e; i += 256)
        atomicAdd(&h[dst[i] >> BSH], 1);
    __syncthreads();
    for (int i = t; i < nbuck; i += 256)
        table[i * NB + b] = h[i];               // bucket-major layout
}

// exclusive scan of each bucket's NB entries; bucket total -> btot
__global__ void kp_scan_table(int* __restrict__ table, int* __restrict__ btot) {
    __shared__ int s[NB];
    int t = threadIdx.x, b = blockIdx.x;
    int v = table[b * NB + t];
    s[t] = v; __syncthreads();
    for (int off = 1; off < NB; off <<= 1) {
        int x = (t >= off) ? s[t - off] : 0;
        __syncthreads();
        s[t] += x;
        __syncthreads();
    }
    table[b * NB + t] = s[t] - v;               // exclusive within bucket
    if (t == NB - 1) btot[b] = s[t];
}

// exclusive scan of bucket totals -> bucketBase; also finalize row_ptr[n]
__global__ void kp_scan_btot(const int* __restrict__ btot, int* __restrict__ bucketBase,
                             int* __restrict__ row_ptr, int nbuck, int E, int n) {
    __shared__ int s[1024];
    int t = threadIdx.x;
    int v = (t < nbuck) ? btot[t] : 0;
    s[t] = v; __syncthreads();
    for (int off = 1; off < 1024; off <<= 1) {
        int x = (t >= off) ? s[t - off] : 0;
        __syncthreads();
        s[t] += x;
        __syncthreads();
    }
    if (t < nbuck) bucketBase[t] = s[t] - v;
    if (t == 0) { bucketBase[nbuck] = E; row_ptr[n] = E; }
}

__global__ __launch_bounds__(256) void kp_scatter(const int* __restrict__ src,
                                                  const int* __restrict__ dst,
                                                  const int* __restrict__ table,
                                                  const int* __restrict__ bucketBase,
                                                  uint* __restrict__ sorted,
                                                  int E, int nbuck, int chunk) {
    __shared__ int off[MAXBUCK];
    int t = threadIdx.x, b = blockIdx.x;
    for (int i = t; i < nbuck; i += 256)
        off[i] = bucketBase[i] + table[i * NB + b];
    __syncthreads();
    int s = b * chunk, e = min(E, s + chunk);
    for (int i = s + t; i < e; i += 256) {
        int d = dst[i];
        int bk = d >> BSH;
        int slot = atomicAdd(&off[bk], 1);      // LDS atomic: unique slot in bucket region
        sorted[slot] = ((uint)src[i] << BSH) | (uint)(d & BMASK);
    }
}

// one block per bucket: local count/scan/rank -> row_ptr, col, dinv
__global__ __launch_bounds__(256) void kp_build(const uint* __restrict__ sorted,
                                                const int* __restrict__ bucketBase,
                                                int* __restrict__ row_ptr,
                                                int* __restrict__ col,
                                                float* __restrict__ dinv, int n) {
    __shared__ int cnt[128], loc[128], cnt2[128];
    int t = threadIdx.x, b = blockIdx.x;
    int base = bucketBase[b], end = bucketBase[b + 1];
    if (t < 128) { cnt[t] = 0; cnt2[t] = 0; }
    __syncthreads();
    for (int i = base + t; i < end; i += 256)
        atomicAdd(&cnt[sorted[i] & BMASK], 1);
    __syncthreads();
    int v = (t < 128) ? cnt[t] : 0;
    if (t < 128) loc[t] = v;
    __syncthreads();
    for (int off = 1; off < 128; off <<= 1) {   // inclusive scan of cnt in loc
        int x = (t >= off && t < 128) ? loc[t - off] : 0;
        __syncthreads();
        if (t < 128) loc[t] += x;
        __syncthreads();
    }
    int node = (b << BSH) + t;
    if (t < 128 && node < n) {
        row_ptr[node] = base + loc[t] - v;      // exclusive prefix
        dinv[node] = rsqrtf((float)(v + 1));    // deg = in-edges + self-loop
    }
    __syncthreads();
    for (int i = base + t; i < end; i += 256) {
        uint p = sorted[i];
        int low = p & BMASK;
        int r = atomicAdd(&cnt2[low], 1);
        col[base + (loc[low] - cnt[low]) + r] = (int)(p >> BSH);
    }
}

// ---------------- bf16 helpers ----------------
__device__ inline uint bf16rn(float f) {               // fp32 -> bf16 bits, round-nearest-even
    uint u = __float_as_uint(f);
    return (u + 0x7fffu + ((u >> 16) & 1u)) >> 16;
}

__device__ inline void accum_bf16x8(float* a, uint4 v) {
    a[0] += __uint_as_float(v.x << 16);
    a[1] += __uint_as_float(v.x & 0xffff0000u);
    a[2] += __uint_as_float(v.y << 16);
    a[3] += __uint_as_float(v.y & 0xffff0000u);
    a[4] += __uint_as_float(v.z << 16);
    a[5] += __uint_as_float(v.z & 0xffff0000u);
    a[6] += __uint_as_float(v.w << 16);
    a[7] += __uint_as_float(v.w & 0xffff0000u);
}

// ---------------- W prep (both layers): Wt_hi/Wt_lo[n][k] (bf16 split) from W[k][n] fp32 ----------------
__global__ void k_prep_w2(const float* __restrict__ W1, const float* __restrict__ W2,
                          ushort* __restrict__ w1h, ushort* __restrict__ w1l,
                          ushort* __restrict__ w2h, ushort* __restrict__ w2l) {
    int i = blockIdx.x * blockDim.x + threadIdx.x;   // 0 .. 2*16384-1
    const float* W;
    ushort *Wh, *Wl;
    int j;
    if (i < D * D) { W = W1; Wh = w1h; Wl = w1l; j = i; }
    else           { W = W2; Wh = w2h; Wl = w2l; j = i - D * D; }
    int k = j >> 7, nn = j & 127;
    float w = W[k * D + nn];
    uint hb = bf16rn(w);
    float hf = __uint_as_float(hb << 16);
    uint lb = bf16rn(w - hf);
    Wh[nn * D + k] = (ushort)hb;
    Wl[nn * D + k] = (ushort)lb;
}

// ---------------- MFMA GEMM: Hb[M,128](bf16) = dinv[r] * (A[M,128] @ W[128,128]) ----------------
// A_FP32: A is fp32, split hi/lo -> 3 passes (AhWh + AlWh + AhWl), error ~2^-18.
// else:   A is bf16 (exact)      -> 2 passes (AhWh + AhWl).
// BK=128 single-stage (one barrier). A in LDS (stride 136 -> 2-way = free);
// W hi/lo fragments loaded directly from global (64KB, L2-resident).
template <bool A_FP32>
__global__ __launch_bounds__(256, 2) void k_gemm_mfma(const void* __restrict__ A,
                                                      const ushort* __restrict__ Wth,
                                                      const ushort* __restrict__ Wtl,
                                                      const float* __restrict__ dinv,
                                                      ushort* __restrict__ Yb, int M) {
    constexpr int STR = 136;                         // LDS row stride in bf16 (16B-aligned rows)
    __shared__ ushort lds[(A_FP32 ? 2 : 1) * 128 * STR];
    ushort* Ah = lds;
    ushort* Al = A_FP32 ? (lds + 128 * STR) : nullptr;

    int t = threadIdx.x;
    int lane = t & 63, wave = t >> 6;
    int quad = lane >> 4, l16 = lane & 15;
    int m_off = (wave & 1) * 64;                     // wave's 64x64 sub-tile
    int n_off = (wave >> 1) * 64;
    int block_row = blockIdx.x * 128;

    f32x4_t acc[4][4];
#pragma unroll
    for (int mt = 0; mt < 4; mt++)
#pragma unroll
        for (int nt = 0; nt < 4; nt++) acc[mt][nt] = (f32x4_t){0.f, 0.f, 0.f, 0.f};

    // ---- stage A (full K=128 in one shot) ----
    if constexpr (A_FP32) {
        const float* Af = (const float*)A;
#pragma unroll
        for (int it = 0; it < 16; it++) {
            int s = t + it * 256;                    // 4096 float4 slots
            int row = s >> 5, kl = (s & 31) * 4;
            int gr = block_row + row;
            float4 v = make_float4(0.f, 0.f, 0.f, 0.f);
            if (gr < M) v = *(const float4*)(Af + (size_t)gr * D + kl);
            ushort4 h, l;
            uint hb, lb; float hf;
            hb = bf16rn(v.x); hf = __uint_as_float(hb << 16); lb = bf16rn(v.x - hf);
            h.x = (ushort)hb; l.x = (ushort)lb;
            hb = bf16rn(v.y); hf = __uint_as_float(hb << 16); lb = bf16rn(v.y - hf);
            h.y = (ushort)hb; l.y = (ushort)lb;
            hb = bf16rn(v.z); hf = __uint_as_float(hb << 16); lb = bf16rn(v.z - hf);
            h.z = (ushort)hb; l.z = (ushort)lb;
            hb = bf16rn(v.w); hf = __uint_as_float(hb << 16); lb = bf16rn(v.w - hf);
            h.w = (ushort)hb; l.w = (ushort)lb;
            *(ushort4*)&Ah[row * STR + kl] = h;
            *(ushort4*)&Al[row * STR + kl] = l;
        }
    } else {
        const ushort* Ab = (const ushort*)A;
#pragma unroll
        for (int it = 0; it < 8; it++) {
            int s = t + it * 256;                    // 2048 16B slots
            int row = s >> 4, kl = (s & 15) * 8;
            int gr = block_row + row;
            uint4 v = make_uint4(0u, 0u, 0u, 0u);
            if (gr < M) v = *(const uint4*)(Ab + (size_t)gr * D + kl);
            *(uint4*)&Ah[row * STR + kl] = v;
        }
    }
    __syncthreads();

    // ---- MFMA over 4 k-steps of 32; B frags straight from global (L2-hot) ----
#pragma unroll
    for (int ks = 0; ks < 4; ks++) {
        int kf = ks * 32 + quad * 8;
        bf16x8_t ah[4], bh[4], bl[4];
#pragma unroll
        for (int mt = 0; mt < 4; mt++)
            ah[mt] = *(const bf16x8_t*)&Ah[(m_off + mt * 16 + l16) * STR + kf];
#pragma unroll
        for (int nt = 0; nt < 4; nt++) {
            size_t wo = (size_t)(n_off + nt * 16 + l16) * D + kf;
            bh[nt] = *(const bf16x8_t*)(Wth + wo);
            bl[nt] = *(const bf16x8_t*)(Wtl + wo);
        }
        if constexpr (A_FP32) {
            bf16x8_t al[4];
#pragma unroll
            for (int mt = 0; mt < 4; mt++)
                al[mt] = *(const bf16x8_t*)&Al[(m_off + mt * 16 + l16) * STR + kf];
#pragma unroll
            for (int mt = 0; mt < 4; mt++)
#pragma unroll
                for (int nt = 0; nt < 4; nt++) {
                    acc[mt][nt] = __builtin_amdgcn_mfma_f32_16x16x32_bf16(ah[mt], bh[nt], acc[mt][nt], 0, 0, 0);
                    acc[mt][nt] = __builtin_amdgcn_mfma_f32_16x16x32_bf16(al[mt], bh[nt], acc[mt][nt], 0, 0, 0);
                    acc[mt][nt] = __builtin_amdgcn_mfma_f32_16x16x32_bf16(ah[mt], bl[nt], acc[mt][nt], 0, 0, 0);
                }
        } else {
#pragma unroll
            for (int mt = 0; mt < 4; mt++)
#pragma unroll
                for (int nt = 0; nt < 4; nt++) {
                    acc[mt][nt] = __builtin_amdgcn_mfma_f32_16x16x32_bf16(ah[mt], bh[nt], acc[mt][nt], 0, 0, 0);
                    acc[mt][nt] = __builtin_amdgcn_mfma_f32_16x16x32_bf16(ah[mt], bl[nt], acc[mt][nt], 0, 0, 0);
                }
        }
    }

    // ---- epilogue: C layout col=lane&15, row=quad*4+reg; scale by dinv, pack bf16 ----
#pragma unroll
    for (int mt = 0; mt < 4; mt++) {
#pragma unroll
        for (int reg = 0; reg < 4; reg++) {
            int gr = block_row + m_off + mt * 16 + quad * 4 + reg;
            if (gr < M) {
                float di = dinv[gr];
#pragma unroll
                for (int nt = 0; nt < 4; nt++) {
                    int colg = n_off + nt * 16 + l16;
                    Yb[(size_t)gr * D + colg] = (ushort)bf16rn(di * acc[mt][nt][reg]);
                }
            }
        }
    }
}

// ---------------- pull aggregation on pre-scaled bf16 H':
//   Y[d] = dinv[d] * (H'[d] + sum_{s in row d} H'[s]) + b   (optional relu; optional bf16 out)
// One wave per node. Quarter-wave (16 lanes x 16B = 256B) per edge row -> 4 chains;
// 2x unroll per chain -> 8 independent row-gathers in flight per wave.
__global__ __launch_bounds__(256) void k_agg(const ushort* __restrict__ Hb,
                                             const int* __restrict__ row_ptr,
                                             const int* __restrict__ col,
                                             const float* __restrict__ dinv,
                                             const float* __restrict__ bias,
                                             float* __restrict__ Yf, ushort* __restrict__ Yb,
                                             int n, int do_relu, int out_bf16) {
    int node = blockIdx.x * 4 + (threadIdx.x >> 6);
    int lane = threadIdx.x & 63;
    int chain = lane >> 4;       // 0..3: which edge chain
    int l16   = lane & 15;       // 16B slot: bf16 cols 8*l16 .. 8*l16+7
    if (node >= n) return;

    int start = row_ptr[node];
    int end   = row_ptr[node + 1];

    float a0[8], a1[8];
#pragma unroll
    for (int k = 0; k < 8; k++) { a0[k] = 0.f; a1[k] = 0.f; }

    if (chain == 0) {            // self-loop row in chain 0
        uint4 v = ((const uint4*)(Hb + (size_t)node * D))[l16];
        accum_bf16x8(a0, v);
    }

    int e = start + chain;
    for (; e + 4 < end; e += 8) {
        int s0 = col[e];
        int s1 = col[e + 4];
        uint4 v0 = ((const uint4*)(Hb + (size_t)s0 * D))[l16];
        uint4 v1 = ((const uint4*)(Hb + (size_t)s1 * D))[l16];
        accum_bf16x8(a0, v0);
        accum_bf16x8(a1, v1);
    }
    if (e < end) {               // at most one tail element per chain
        int s0 = col[e];
        uint4 v0 = ((const uint4*)(Hb + (size_t)s0 * D))[l16];
        accum_bf16x8(a0, v0);
    }

    float acc[8];
#pragma unroll
    for (int k = 0; k < 8; k++) {
        float v = a0[k] + a1[k];
        v += __shfl_xor(v, 16, 64);   // combine chains 0<->1, 2<->3
        v += __shfl_xor(v, 32, 64);   // combine pairs
        acc[k] = v;
    }

    if (chain == 0) {            // lanes 0..15 hold the full row (cols 8*l16..8*l16+7)
        float di = dinv[node];
        const float4* bp = (const float4*)bias + l16 * 2;
        float4 b0 = bp[0], b1 = bp[1];
        float o[8];
        o[0] = fmaf(di, acc[0], b0.x); o[1] = fmaf(di, acc[1], b0.y);
        o[2] = fmaf(di, acc[2], b0.z); o[3] = fmaf(di, acc[3], b0.w);
        o[4] = fmaf(di, acc[4], b1.x); o[5] = fmaf(di, acc[5], b1.y);
        o[6] = fmaf(di, acc[6], b1.z); o[7] = fmaf(di, acc[7], b1.w);
        if (do_relu) {
#pragma unroll
            for (int k = 0; k < 8; k++) o[k] = fmaxf(o[k], 0.f);
        }
        if (out_bf16) {
            uint4 pk;
            pk.x = bf16rn(o[0]) | (bf16rn(o[1]) << 16);
            pk.y = bf16rn(o[2]) | (bf16rn(o[3]) << 16);
            pk.z = bf16rn(o[4]) | (bf16rn(o[5]) << 16);
            pk.w = bf16rn(o[6]) | (bf16rn(o[7]) << 16);
            ((uint4*)(Yb + (size_t)node * D))[l16] = pk;
        } else {
            float4* yp = (float4*)(Yf + (size_t)node * D) + l16 * 2;
            yp[0] = make_float4(o[0], o[1], o[2], o[3]);
            yp[1] = make_float4(o[4], o[5], o[6], o[7]);
        }
    }
}

// ---------------- host ----------------
extern "C" void kernel_launch(void* const* d_in, const int* in_sizes, int n_in,
                              void* d_out, int out_size, void* d_ws, size_t ws_size,
                              hipStream_t stream) {
    const float* x  = (const float*)d_in[0];
    const int*   ei = (const int*)d_in[1];
    const float* W1 = (const float*)d_in[2];
    const float* b1 = (const float*)d_in[3];
    const float* W2 = (const float*)d_in[4];
    const float* b2 = (const float*)d_in[5];
    float* out = (float*)d_out;

    int n = in_sizes[0] / D;       // 100000
    int E = in_sizes[1] / 2;       // 1600000
    const int* src = ei;
    const int* dst = ei + E;

    char* p = (char*)d_ws;
    ushort* h_buf = (ushort*)p; p += (size_t)n * D * sizeof(ushort);   // bf16 H'
    ushort* y_buf = (ushort*)p; p += (size_t)n * D * sizeof(ushort);   // bf16 y
    ushort* w1h   = (ushort*)p; p += (size_t)D * D * sizeof(ushort);
    ushort* w1l   = (ushort*)p; p += (size_t)D * D * sizeof(ushort);
    ushort* w2h   = (ushort*)p; p += (size_t)D * D * sizeof(ushort);
    ushort* w2l   = (ushort*)p; p += (size_t)D * D * sizeof(ushort);
    float* dinv   = (float*)p;  p += (size_t)n * sizeof(float);
    int*   row_ptr= (int*)p;    p += (size_t)(n + 1) * sizeof(int);
    int*   table  = (int*)p;    p += (size_t)MAXBUCK * NB * sizeof(int);
    int*   btot   = (int*)p;    p += (size_t)MAXBUCK * sizeof(int);
    int*   bbase  = (int*)p;    p += (size_t)(MAXBUCK + 1) * sizeof(int);
    uint*  sorted = (uint*)p;   p += (size_t)E * sizeof(uint);
    int*   col    = (int*)p;    p += (size_t)E * sizeof(int);

    int nbuck = (n + BMASK) >> BSH;                  // 782
    int chunk = (E + NB - 1) / NB;                   // 6250

    kp_hist<<<NB, 256, 0, stream>>>(dst, table, E, nbuck, chunk);
    kp_scan_table<<<nbuck, NB, 0, stream>>>(table, btot);
    kp_scan_btot<<<1, 1024, 0, stream>>>(btot, bbase, row_ptr, nbuck, E, n);
    kp_scatter<<<NB, 256, 0, stream>>>(src, dst, table, bbase, sorted, E, nbuck, chunk);
    kp_build<<<nbuck, 256, 0, stream>>>(sorted, bbase, row_ptr, col, dinv, n);

    k_prep_w2<<<(2 * D * D) / 256, 256, 0, stream>>>(W1, W2, w1h, w1l, w2h, w2l);

    int gemm_grid = (n + 127) / 128;
    int agg_grid  = (n + 3) / 4;

    // layer 1: h' = bf16(dinv * (x@W1)) ; y = bf16(relu(dinv * (A_sum h') + b1))
    k_gemm_mfma<true><<<gemm_grid, 256, 0, stream>>>(x, w1h, w1l, dinv, h_buf, n);
    k_agg<<<agg_grid, 256, 0, stream>>>(h_buf, row_ptr, col, dinv, b1, nullptr, y_buf, n, 1, 1);
    // layer 2: h2' = bf16(dinv * (y@W2)) ; out = dinv * (A_sum h2') + b2
    k_gemm_mfma<false><<<gemm_grid, 256, 0, stream>>>(y_buf, w2h, w2l, dinv, h_buf, n);
    k_agg<<<agg_grid, 256, 0, stream>>>(h_buf, row_ptr, col, dinv, b2, out, nullptr, n, 0, 0);
}